// Round 1
// baseline (89.793 us; speedup 1.0000x reference)
//
#include <hip/hip_runtime.h>

#define VDIM   32
#define NPAIR  496              // 32*31/2
#define NBASIS 14               // DEG + ORDER - 1
#define NPARAM (NBASIS * NPAIR) // 6944
#define ROWS   16               // rows per block
#define SPS    15               // pair-major param stride (odd -> bank spread)

typedef float f32x4 __attribute__((ext_vector_type(4)));

// u = (x - t0)/dist with t0 = LO - 3*dist, dist = 30/11.  -t0/dist == 8.5 exactly.
__device__ __forceinline__ float spline_u(float xi) {
    const float invd = 11.0f / 30.0f;
    float x = fminf(fmaxf(xi, -15.0f), 15.0f - 1e-6f);
    return x * invd + 8.5f;
}

// 1024 blocks x 256 threads; block stages params (pair-major) + 16 rows of
// inputs/weights into LDS, then emits 16 rows of lm via f32x4 NT stores.
__global__ __launch_bounds__(256) void Decorrelation_35270271435435_kernel(
    const float* __restrict__ input,    // [N,32]
    const float* __restrict__ params,   // [14,496] k-major
    float* __restrict__ out,            // [N,32]
    float* __restrict__ lm,             // [N,32,32]
    float* __restrict__ pens,           // [3]
    int N)
{
    __shared__ float sp[NPAIR * SPS];        // 29.0 KB pair-major params
    __shared__ float xin[ROWS][VDIM];        // raw inputs (out = lm@x uses raw x)
    __shared__ f32x4 wgt4[ROWS][VDIM];       // column-swizzled weight vectors

    const int tid = threadIdx.x;
    const int n0  = blockIdx.x * ROWS;

    // ---- Stage params into LDS, transposed to pair-major stride-15 ----
    {
        const f32x4* p4 = (const f32x4*)params;
        for (int i4 = tid; i4 < NPARAM / 4; i4 += 256) {
            const f32x4 val = p4[i4];        // coalesced global read
            const int base = i4 * 4;
            #pragma unroll
            for (int e = 0; e < 4; ++e) {
                const int idx = base + e;
                const int k = idx / NPAIR;   // magic-mul, setup only
                const int p = idx - k * NPAIR;
                sp[p * SPS + k] = val[e];    // stride-15 scatter: conflict-light
            }
        }
    }

    // ---- Inputs + cubic B-spline weight vectors: 512 items, 2/thread ----
    #pragma unroll
    for (int it = 0; it < 2; ++it) {
        const int item = tid + it * 256;
        const int r = item >> 5, c = item & 31;
        const int n = n0 + r;
        const float xi = (n < N) ? input[n * VDIM + c] : 0.0f;
        xin[r][c] = xi;
        const float u  = spline_u(xi);
        float fi = floorf(u);
        fi = fminf(fmaxf(fi, 3.0f), 13.0f);
        const float uu  = u - fi;
        const float om  = 1.0f - uu;
        const float uu2 = uu * uu, uu3 = uu2 * uu;
        const float sixth = 1.0f / 6.0f;
        f32x4 w;
        w[0] = om * om * om * sixth;
        w[1] = (3.0f * uu3 - 6.0f * uu2 + 4.0f) * sixth;
        w[2] = (-3.0f * uu3 + 3.0f * uu2 + 3.0f * uu + 1.0f) * sixth;
        w[3] = uu3 * sixth;
        // swizzle so the row-loop read (j<<3)|t walks 8 distinct bank-quads
        wgt4[r][((c & 3) << 3) | (c >> 2)] = w;
    }
    __syncthreads();

    // ---- Per-thread constants (row-invariant) ----
    const int v  = tid >> 3;          // lm row this thread serves
    const int t  = tid & 7;
    const int c0 = t << 2;            // first of 4 consecutive cols
    int  pb[4];
    bool low[4], dia[4];
    #pragma unroll
    for (int j = 0; j < 4; ++j) {
        const int c = c0 + j;
        low[j] = (c < v);
        dia[j] = (c == v);
        pb[j]  = ((v * (v - 1)) / 2 + c) * SPS;   // tril_indices(-1) flat order
    }

    const int rlim = (N - n0 < ROWS) ? (N - n0) : ROWS;
    float* lmp = lm + (size_t)n0 * (VDIM * VDIM) + tid * 4;

    #pragma unroll 4
    for (int r = 0; r < ROWS; ++r, lmp += VDIM * VDIM) {
        const f32x4 x4 = *(const f32x4*)&xin[r][c0];   // one ds_read_b128
        float vals[4];
        float partial = 0.0f;
        #pragma unroll
        for (int j = 0; j < 4; ++j) {
            float val = 0.0f;
            if (dia[j]) {
                val = 1.0f;
            } else if (low[j]) {
                // recompute interval from x (cheap VALU) instead of LDS ib[]
                const float u = spline_u(x4[j]);
                float fi = floorf(u);
                fi = fminf(fmaxf(fi, 3.0f), 13.0f);
                const int k0 = (int)fi - 3;
                const float* q = &sp[pb[j] + k0];      // 4 contiguous taps
                const f32x4 w = wgt4[r][(j << 3) | t]; // conflict-free b128
                val = w[0] * q[0] + w[1] * q[1] + w[2] * q[2] + w[3] * q[3];
            }
            vals[j] = val;
            partial += val * x4[j];
        }
        if (r < rlim) {
            const f32x4 f4 = { vals[0], vals[1], vals[2], vals[3] };
            __builtin_nontemporal_store(f4, (f32x4*)lmp);
            partial += __shfl_down(partial, 4, 8);
            partial += __shfl_down(partial, 2, 8);
            partial += __shfl_down(partial, 1, 8);
            if (t == 0) out[(size_t)(n0 + r) * VDIM + v] = partial;
        }
    }

    // ---- Penalty scalars (block 0 only; pair-major chains, all static idx) ----
    if (blockIdx.x == 0) {
        float s2 = 0.0f, s1 = 0.0f, spn = 0.0f;
        for (int p = tid; p < NPAIR; p += 256) {
            const float* q = &sp[p * SPS];
            float a[NBASIS];
            #pragma unroll
            for (int k = 0; k < NBASIS; ++k) { a[k] = q[k]; spn += a[k] * a[k]; }
            #pragma unroll
            for (int k = 0; k < NBASIS - 1; ++k) {
                const float d = a[k + 1] - a[k];
                s1 += d * d;
            }
            #pragma unroll
            for (int k = 0; k < NBASIS - 2; ++k) {
                const float d = a[k + 2] - 2.0f * a[k + 1] + a[k];
                s2 += d * d;
            }
        }
        #pragma unroll
        for (int off = 32; off > 0; off >>= 1) {
            s2  += __shfl_down(s2, off);
            s1  += __shfl_down(s1, off);
            spn += __shfl_down(spn, off);
        }
        __shared__ float wsum[3][4];
        const int lane = tid & 63, wid = tid >> 6;
        if (lane == 0) { wsum[0][wid] = s2; wsum[1][wid] = s1; wsum[2][wid] = spn; }
        __syncthreads();
        if (tid == 0) {
            pens[0] = wsum[0][0] + wsum[0][1] + wsum[0][2] + wsum[0][3];
            pens[1] = wsum[1][0] + wsum[1][1] + wsum[1][2] + wsum[1][3];
            pens[2] = wsum[2][0] + wsum[2][1] + wsum[2][2] + wsum[2][3];
        }
    }
}

extern "C" void kernel_launch(void* const* d_in, const int* in_sizes, int n_in,
                              void* d_out, int out_size, void* d_ws, size_t ws_size,
                              hipStream_t stream) {
    const float* input  = (const float*)d_in[0];   // [N,32]
    // d_in[1] = log_d : unused by the reference
    const float* params = (const float*)d_in[2];   // [14,496]
    const int N = in_sizes[0] / VDIM;              // 16384

    float* out  = (float*)d_out;                   // [N,32]
    float* lm   = out + (size_t)N * VDIM;          // [N,32,32]
    float* pens = lm + (size_t)N * VDIM * VDIM;    // [3]

    const int nb = (N + ROWS - 1) / ROWS;          // 1024
    Decorrelation_35270271435435_kernel<<<nb, 256, 0, stream>>>(
        input, params, out, lm, pens, N);
}